// Round 6
// baseline (1374.012 us; speedup 1.0000x reference)
//
#include <hip/hip_runtime.h>
#include <math.h>

// Problem constants
constexpr int DIM    = 2048;
constexpr int NEXP   = 64;
constexpr int TOPK   = 8;
constexpr int T_TOT  = 32768;        // 4 * 8192 tokens

// Tiling: lane=token (64/wave), wave owns 16 experts, K-chunk 32
constexpr int TTILE  = 64;           // tokens per block
constexpr int KC     = 32;           // k-chunk
constexpr int NSTEP  = DIM / KC;     // 64
constexpr int PSTR   = 260;          // padded chunk stride (floats): 260%32=4 -> bank rotation

// Ambiguity guard: f32-vs-exact score deviation is ~1e-6 rms (hard bound <6e-5).
// Any token whose sorted top-9 has an adjacent gap below this is re-resolved in f64.
constexpr float GAP_TH = 5.0e-4f;

// Output layout (float32, reference return order)
constexpr size_t OFF_W   = 0;                      // top_w   [T,8]
constexpr size_t OFF_IDX = (size_t)T_TOT * TOPK;   // top_idx [T,8] (as float)
constexpr size_t OFF_B   = OFF_IDX * 2;            // new_adaptive_bias [64]
constexpr size_t OFF_U   = OFF_B + NEXP;           // new_expert_usage  [64]

// ws (uint32) layout: [0..63] expert counts | [64] n_flagged | [65..] flagged ids
// Capacity of the flagged list is computed HOST-SIDE from the real ws_size.

__global__ __launch_bounds__(256, 2)
void moe_gate_main(const float* __restrict__ x,
                   const float* __restrict__ gw,
                   const float* __restrict__ bias,
                   float* __restrict__ out,
                   unsigned int* __restrict__ ws,
                   const unsigned int cap)
{
    // X double-buffer [2][8 chunks][260 floats] = 4160 floats = 16640 B,
    // exactly overlaid later by scores S[64][65] = 4160 floats.
    __shared__ __align__(16) float smem[4160];
    __shared__ unsigned int hist[NEXP];

    const int tid  = threadIdx.x;
    const int t0   = blockIdx.x * TTILE;
    const int lane = tid & 63;

    if (tid < NEXP) hist[tid] = 0;

    // Wave-uniform expert base: wave wv owns experts 16*wv .. 16*wv+15.
    const int wv = __builtin_amdgcn_readfirstlane(tid >> 6);
    const float* wbase = gw + (size_t)(16 * wv) * DIM;

    // ---- staging geometry: 2 float4 per thread per step (64 tok x 32 k) ----
    // f = tid (+256): tok = f>>3 (0..63), c = f&7 (16B chunk within 32-float row).
    // Global: 8 lanes cover one contiguous 128B row slice (coalesced).
    // LDS chunk-major [c][tok]: write banks spread (c+tok)&7 -> b128 floor;
    // read (fixed c, addr linear in lane) -> conflict-free floor.
    const int tokA = tid >> 3;                     // 0..31
    const int cA   = tid & 7;
    const float* xgA = x + (size_t)(t0 + tokA)      * DIM + 4 * cA;
    const float* xgB = x + (size_t)(t0 + tokA + 32) * DIM + 4 * cA;
    const int lsA = cA * PSTR + tokA * 4;          // float index in buffer
    const int lsB = cA * PSTR + (tokA + 32) * 4;

    float acc[16];
    #pragma unroll
    for (int i = 0; i < 16; ++i) acc[i] = 0.0f;

    // prologue: stage step 0 into buffer 0
    {
        const float4 a = *(const float4*)xgA;
        const float4 b = *(const float4*)xgB;
        *(float4*)&smem[lsA] = a;
        *(float4*)&smem[lsB] = b;
    }

    for (int s = 0; s < NSTEP; ++s) {
        __syncthreads();                           // buf[s&1] staged; prior reads done
        const int cur = (s & 1) * 2080;

        // next tile's global loads fly under this step's compute
        float4 nxa, nxb;
        if (s + 1 < NSTEP) {
            nxa = *(const float4*)(xgA + (s + 1) * KC);
            nxb = *(const float4*)(xgB + (s + 1) * KC);
        }

        // my token's 32 x-values -> registers (reused by all 16 experts)
        float xr[32];
        #pragma unroll
        for (int c = 0; c < 8; ++c)
            *(float4*)&xr[4 * c] = *(const float4*)&smem[cur + c * PSTR + lane * 4];

        // experts: wave-uniform W loads (scalar/broadcast path), double-buffered
        // across the expert loop; two independent 16-deep FMA chains per expert.
        const float* wk = wbase + s * KC;
        float wA[32], wB[32];
        #pragma unroll
        for (int j = 0; j < 8; ++j)
            *(float4*)&wA[4 * j] = *(const float4*)(wk + 4 * j);
        #pragma unroll
        for (int e = 0; e < 16; ++e) {
            const float* wc = (e & 1) ? wB : wA;   // e is compile-time (full unroll)
            float*       wn = (e & 1) ? wA : wB;
            if (e < 15) {
                const float* wp = wk + (size_t)(e + 1) * DIM;
                #pragma unroll
                for (int j = 0; j < 8; ++j)
                    *(float4*)&wn[4 * j] = *(const float4*)(wp + 4 * j);
            }
            float a0 = acc[e], a1 = 0.0f;
            #pragma unroll
            for (int k = 0; k < 16; ++k) {
                a0 = fmaf(wc[k],      xr[k],      a0);
                a1 = fmaf(wc[k + 16], xr[k + 16], a1);
            }
            acc[e] = a0 + a1;
        }

        if (s + 1 < NSTEP) {                       // stage next buffer (other half)
            const int nb = ((s + 1) & 1) * 2080;
            *(float4*)&smem[nb + lsA] = nxa;
            *(float4*)&smem[nb + lsB] = nxb;
        }
    }

    // ---- dump scores (+bias) to LDS: S[e][t], stride 65 floats (overlays X) ----
    __syncthreads();                               // all waves done reading X bufs
    float* S = smem;
    #pragma unroll
    for (int i = 0; i < 16; ++i) {
        const int e = 16 * wv + i;
        S[e * 65 + lane] = acc[i] + bias[e];       // lanes write contiguous 256B row
    }
    __syncthreads();

    if (tid < TTILE) {
        const int t = tid;
        // top-9 (descending, lowest index first on ties — strict '>')
        float bv[9]; int bi[9];
        #pragma unroll
        for (int j = 0; j < 9; ++j) { bv[j] = -INFINITY; bi[j] = 0; }
        for (int e = 0; e < NEXP; ++e) {
            const float v = S[e * 65 + t];
            if (v > bv[8]) {
                bv[8] = v; bi[8] = e;
                #pragma unroll
                for (int j = 8; j > 0; --j) {
                    if (bv[j] > bv[j - 1]) {
                        const float tv = bv[j]; bv[j] = bv[j-1]; bv[j-1] = tv;
                        const int   ti = bi[j]; bi[j] = bi[j-1]; bi[j-1] = ti;
                    }
                }
            }
        }
        // ambiguity: any adjacent gap in sorted top-9 below guard -> f64 refine
        float ming = bv[0] - bv[1];
        #pragma unroll
        for (int j = 1; j < 8; ++j) ming = fminf(ming, bv[j] - bv[j + 1]);
        bool amb = (ming < GAP_TH);

        if (amb) {
            const unsigned slot = atomicAdd(ws + NEXP, 1u);
            if (slot < cap) ws[NEXP + 1 + slot] = (unsigned)(t0 + t);
            else            amb = false;           // list full: fall back to f32 result
        }

        const float m = bv[0];
        float Z = 0.0f;
        for (int e = 0; e < NEXP; ++e) Z += expf(S[e * 65 + t] - m);
        const float rZ = 1.0f / Z;
        float p[TOPK]; float wsum = 0.0f;
        #pragma unroll
        for (int j = 0; j < TOPK; ++j) { p[j] = expf(bv[j] - m) * rZ; wsum += p[j]; }
        const float rd = 1.0f / (wsum + 1e-8f);

        const size_t tglob = (size_t)(t0 + t);
        float4 w0 = { p[0]*rd, p[1]*rd, p[2]*rd, p[3]*rd };
        float4 w1 = { p[4]*rd, p[5]*rd, p[6]*rd, p[7]*rd };
        *(float4*)(out + OFF_W + tglob * TOPK)     = w0;
        *(float4*)(out + OFF_W + tglob * TOPK + 4) = w1;
        float4 i0 = { (float)bi[0], (float)bi[1], (float)bi[2], (float)bi[3] };
        float4 i1 = { (float)bi[4], (float)bi[5], (float)bi[6], (float)bi[7] };
        *(float4*)(out + OFF_IDX + tglob * TOPK)     = i0;
        *(float4*)(out + OFF_IDX + tglob * TOPK + 4) = i1;

        if (!amb) {
            #pragma unroll
            for (int j = 0; j < TOPK; ++j) atomicAdd(&hist[bi[j]], 1u);
        }
    }

    __syncthreads();
    if (tid < NEXP) atomicAdd(ws + tid, hist[tid]);
}

// f64 re-resolve of flagged tokens: identical math/rounding/tie semantics as the
// previously-passing f64 kernel ((float)acc + bias, strict-> insertion, expf softmax).
// DO NOT change summation order: index outputs must match reference exactly.
__global__ __launch_bounds__(256)
void moe_gate_refine(const float* __restrict__ x,
                     const float* __restrict__ gw,
                     const float* __restrict__ bias,
                     float* __restrict__ out,
                     unsigned int* __restrict__ ws,
                     const unsigned int cap)
{
    __shared__ __align__(16) float xs[DIM];
    __shared__ float S[NEXP];
    const unsigned nf = ws[NEXP];
    const unsigned nflag = nf < cap ? nf : cap;
    const unsigned* list = ws + NEXP + 1;

    for (unsigned ii = blockIdx.x; ii < nflag; ii += gridDim.x) {
        const size_t t = (size_t)list[ii];
        __syncthreads();                         // protect xs/S reuse across iters
        #pragma unroll
        for (int jj = 0; jj < 2; ++jj) {
            const int f = threadIdx.x + jj * 256;     // float4 index 0..511
            ((float4*)xs)[f] = ((const float4*)(x + t * DIM))[f];
        }
        __syncthreads();

        const int e = threadIdx.x >> 2;          // 4 threads per expert
        const int q = threadIdx.x & 3;
        const float* wr = gw + (size_t)e * DIM + q * 512;
        const float* xr = xs + q * 512;
        double s = 0.0;
        for (int k = 0; k < 512; k += 4) {
            const float4 wv4 = *(const float4*)(wr + k);
            const float4 xv4 = *(const float4*)(xr + k);
            s = fma((double)wv4.x, (double)xv4.x, s);
            s = fma((double)wv4.y, (double)xv4.y, s);
            s = fma((double)wv4.z, (double)xv4.z, s);
            s = fma((double)wv4.w, (double)xv4.w, s);
        }
        s += __shfl_down(s, 2, 4);
        s += __shfl_down(s, 1, 4);
        if (q == 0) S[e] = (float)s + bias[e];
        __syncthreads();

        if (threadIdx.x == 0) {
            float bv[TOPK]; int bi[TOPK];
            #pragma unroll
            for (int j = 0; j < TOPK; ++j) { bv[j] = -INFINITY; bi[j] = 0; }
            for (int e2 = 0; e2 < NEXP; ++e2) {
                const float v = S[e2];
                if (v > bv[TOPK - 1]) {
                    bv[TOPK - 1] = v; bi[TOPK - 1] = e2;
                    #pragma unroll
                    for (int j = TOPK - 1; j > 0; --j) {
                        if (bv[j] > bv[j - 1]) {
                            const float tv = bv[j]; bv[j] = bv[j-1]; bv[j-1] = tv;
                            const int   ti = bi[j]; bi[j] = bi[j-1]; bi[j-1] = ti;
                        }
                    }
                }
            }
            const float m = bv[0];
            float Z = 0.0f;
            for (int e2 = 0; e2 < NEXP; ++e2) Z += expf(S[e2] - m);
            const float rZ = 1.0f / Z;
            float p[TOPK]; float wsum = 0.0f;
            #pragma unroll
            for (int j = 0; j < TOPK; ++j) { p[j] = expf(bv[j] - m) * rZ; wsum += p[j]; }
            const float rd = 1.0f / (wsum + 1e-8f);

            float4 w0 = { p[0]*rd, p[1]*rd, p[2]*rd, p[3]*rd };
            float4 w1 = { p[4]*rd, p[5]*rd, p[6]*rd, p[7]*rd };
            *(float4*)(out + OFF_W + t * TOPK)     = w0;
            *(float4*)(out + OFF_W + t * TOPK + 4) = w1;
            float4 i0 = { (float)bi[0], (float)bi[1], (float)bi[2], (float)bi[3] };
            float4 i1 = { (float)bi[4], (float)bi[5], (float)bi[6], (float)bi[7] };
            *(float4*)(out + OFF_IDX + t * TOPK)     = i0;
            *(float4*)(out + OFF_IDX + t * TOPK + 4) = i1;

            #pragma unroll
            for (int j = 0; j < TOPK; ++j) atomicAdd(ws + bi[j], 1u);
        }
    }
}

__global__ void moe_gate_fin(const unsigned int* __restrict__ cnt,
                             const float* __restrict__ bias,
                             const float* __restrict__ eu,
                             float* __restrict__ out)
{
    const int e = threadIdx.x;
    const float usage = (float)cnt[e] * (1.0f / (float)(T_TOT * TOPK));
    out[OFF_B + e] = bias[e] - 0.01f * (usage - 1.0f / (float)NEXP);
    out[OFF_U + e] = 0.9f * eu[e] + 0.1f * usage;
}

extern "C" void kernel_launch(void* const* d_in, const int* in_sizes, int n_in,
                              void* d_out, int out_size, void* d_ws, size_t ws_size,
                              hipStream_t stream) {
    const float* x    = (const float*)d_in[0];
    const float* gw   = (const float*)d_in[1];
    const float* bias = (const float*)d_in[2];
    const float* eu   = (const float*)d_in[3];
    float* out = (float*)d_out;
    unsigned int* cnt = (unsigned int*)d_ws;

    // flag-list capacity from the REAL workspace size (no unchecked OOB possible)
    const size_t ws_words = ws_size / sizeof(unsigned int);
    const unsigned cap = ws_words > (size_t)(NEXP + 1)
                       ? (unsigned)(ws_words - (NEXP + 1)) : 0u;

    hipMemsetAsync(cnt, 0, (NEXP + 1) * sizeof(unsigned int), stream);
    moe_gate_main<<<T_TOT / TTILE, 256, 0, stream>>>(x, gw, bias, out, cnt, cap);
    moe_gate_refine<<<256, 256, 0, stream>>>(x, gw, bias, out, cnt, cap);
    moe_gate_fin<<<1, NEXP, 0, stream>>>(cnt, bias, eu, out);
}